// Round 6
// baseline (2466.536 us; speedup 1.0000x reference)
//
#include <hip/hip_runtime.h>
#include <math.h>

// SNN: 5 LIF layers, B=2048, dims 100->128->256->512->1024->784, 25 steps.
// Round 13: kill the K-loop barriers entirely. Rounds 10-12 established the
// double-buffer path is structure-bound (~3600 cyc per K-tile iteration vs
// ~200 cyc of work; S=2 batching, n-split, and occupancy changes all failed
// to move it). New design: the FULL hi/lo weight panel is LDS-resident for
// every layer (<=64KB, proven dynamic-LDS size), staged once behind a single
// barrier; the 25-step loop is then barrier-FREE -- A-fragment loads
// prefetch across tiles AND steps, B reads hit LDS with the proven swizzle,
// Wc is never re-fetched. Per-layer geometry: block 128 x (16*NF), 4 waves
// = 4 m-strips of 32 rows, wave tile 32x(16*NF):
//   L2: NF=2, NK=2  (16KB)  grid 16x8    L3: NF=2, NK=4  (32KB) grid 16x16
//   L4: NF=2, NK=8  (64KB)  grid 16x32   L5: NF=1, NK=16 (64KB) grid 16x49
// m-tiles = 16 (16%8==0): XCD = lb%8 = m-tile%8, A-sharers colocate per XCD
// (verified round 10: FETCH halved). Numerics bit-identical (same K-order).

typedef _Float16 f16;
typedef __attribute__((ext_vector_type(8))) short short8;
typedef __attribute__((ext_vector_type(8))) _Float16 half8;
typedef __attribute__((ext_vector_type(4))) _Float16 half4;
typedef __attribute__((ext_vector_type(4))) float f32x4;

#define B_TOTAL 2048
#define LO_SCALE 2.44140625e-4f  // 2^-12, undoes the lo x2^12 storage scale
#define ACC_SCALE 0.015625f      // 2^-6, undoes the x64 weight pre-scale

// ---------- fp32 64x64 GEMM + relu (layer-1 current, runs once) ------------
__global__ __launch_bounds__(256) void gemm_relu_f32_kernel(
    const float* __restrict__ h, const float* __restrict__ W,
    const float* __restrict__ bias, float* __restrict__ out, int N, int K) {
  __shared__ float As[16][64];
  __shared__ float Bs[16][64];

  const int t = threadIdx.x;
  const int tx = t & 15;
  const int ty = t >> 4;
  const int m0 = blockIdx.y * 64;
  const int n0 = blockIdx.x * 64;
  const int lr = t >> 2;
  const int lc = (t & 3) * 4;

  float acc[4][4];
#pragma unroll
  for (int i = 0; i < 4; ++i)
#pragma unroll
    for (int j = 0; j < 4; ++j) acc[i][j] = 0.0f;

  const int ktiles = (K + 15) / 16;
  for (int kt = 0; kt < ktiles; ++kt) {
    const int kbase = kt * 16;
    {
      const float* src = h + (size_t)(m0 + lr) * K + kbase + lc;
#pragma unroll
      for (int j = 0; j < 4; ++j) {
        const int kg = kbase + lc + j;
        As[lc + j][lr] = (kg < K) ? src[j] : 0.0f;
      }
    }
    {
      const int nr = n0 + lr;
      const float* src = W + (size_t)nr * K + kbase + lc;
#pragma unroll
      for (int j = 0; j < 4; ++j) {
        const int kg = kbase + lc + j;
        Bs[lc + j][lr] = (nr < N && kg < K) ? src[j] : 0.0f;
      }
    }
    __syncthreads();
#pragma unroll
    for (int k = 0; k < 16; ++k) {
      float a[4], bb[4];
#pragma unroll
      for (int i = 0; i < 4; ++i) a[i] = As[k][ty * 4 + i];
#pragma unroll
      for (int j = 0; j < 4; ++j) bb[j] = Bs[k][tx * 4 + j];
#pragma unroll
      for (int i = 0; i < 4; ++i)
#pragma unroll
        for (int j = 0; j < 4; ++j) acc[i][j] = fmaf(a[i], bb[j], acc[i][j]);
    }
    __syncthreads();
  }

#pragma unroll
  for (int i = 0; i < 4; ++i) {
    const int m = m0 + ty * 4 + i;
#pragma unroll
    for (int j = 0; j < 4; ++j) {
      const int n = n0 + tx * 4 + j;
      if (n < N) {
        float cur = acc[i][j] + bias[n];
        out[(size_t)m * N + n] = cur > 0.0f ? cur : 0.0f;
      }
    }
  }
}

// ---------- f16 2-split: W fp32 [N,K] -> Wc f16 [N, 2K] = [hi | lo*2^12] ---
__global__ __launch_bounds__(256) void split2_kernel(
    const float* __restrict__ W, f16* __restrict__ Wc, int total, int K) {
  const int idx = blockIdx.x * 256 + threadIdx.x;
  if (idx < total) {
    const int n = idx / K;
    const int k = idx - n * K;
    const float w64 = W[idx] * 64.0f;
    const f16 hi = (f16)w64;
    const float r = w64 - (float)hi;
    const f16 lo = (f16)(r * 4096.0f);
    const size_t base = (size_t)n * 2 * K + k;
    Wc[base] = hi;
    Wc[base + K] = lo;
  }
}

// ---------- lif1: full 25-step recurrence, cur1 is step-invariant ----------
__global__ __launch_bounds__(256) void lif1_kernel(
    const float* __restrict__ cur1, f16* __restrict__ s1_all) {
  const int i0 = (blockIdx.x * 256 + (int)threadIdx.x) * 4;
  const float4 c = *(const float4*)(cur1 + i0);
  const float ca[4] = {c.x, c.y, c.z, c.w};
  float m[4] = {0.0f, 0.0f, 0.0f, 0.0f};
  for (int st = 0; st < 25; ++st) {
    half4 sv;
#pragma unroll
    for (int j = 0; j < 4; ++j) {
      const float mo = m[j];
      const float reset = (mo - 1.0f > 0.0f) ? 1.0f : 0.0f;
      float mn = __fmul_rn(0.95f, mo);
      mn = __fadd_rn(mn, ca[j]);
      mn = __fsub_rn(mn, reset);
      m[j] = mn;
      sv[j] = (f16)((mn - 1.0f > 0.0f) ? 1.0f : 0.0f);
    }
    *(half4*)(s1_all + (size_t)st * (B_TOTAL * 128) + i0) = sv;
  }
}

// ---------- per-layer GEMM + LIF, 25 steps, fully-resident B panel ---------
// Block tile 128 x (16*NF); 4 waves = 4 m-strips of 32 rows; wave tile
// 32 x (16*NF) via 16x16x32 MFMA (2 m-frags x NF n-frags, hi+lo accs).
// LDS: NK swizzled K-64 tiles; tile = 32*NF rows (hi rows then lo rows)
// x 64 f16. Staged ONCE, single barrier, then 25 steps barrier-free.
// mem state lives in registers for all 25 steps.
// XCD mapping: m-tile = lb&15, n-tile = lb>>4 (16%8==0 -> XCD = m%8).
template <int NK, int NF>
__global__ __launch_bounds__(256) void layer_kernel(
    const f16* __restrict__ A_all,   // [25][2048][K] input spikes
    const f16* __restrict__ Wc,      // [N][2K] = [hi | lo]
    const float* __restrict__ bias,
    f16* __restrict__ spk_out,       // [25][2048][N]   (mode 0)
    float* __restrict__ sr, float* __restrict__ mr,  // [25][2048][N] (mode 1)
    int N, int K, int mode) {
  extern __shared__ f16 Bsm[];
  constexpr int TROWS = 32 * NF;   // rows per K-tile (hi block + lo block)
  constexpr int TILE = TROWS * 64; // f16 per K-tile

  const int t = threadIdx.x;
  const int lane = t & 63;
  const int wm = t >> 6;           // m-strip 0..3
  const int lb = blockIdx.x;
  const int m0 = (lb & 15) * 128;  // XCD = lb%8 = m-tile%8
  const int n0 = (lb >> 4) * (16 * NF);
  const int lrow = t >> 3;         // 0..31 staging row
  const int lk = (t & 7) * 8;      // staging f16 col chunk
  const int K2 = 2 * K;

  // bias per owned column (all n in range: N is an exact tile multiple)
  float bias_r[NF];
#pragma unroll
  for (int j = 0; j < NF; ++j) bias_r[j] = bias[n0 + j * 16 + (lane & 15)];

  // accumulators + membrane state (registers, persistent across 25 steps)
  f32x4 acch[2][NF], accl[2][NF], memr[2][NF];
#pragma unroll
  for (int i = 0; i < 2; ++i)
#pragma unroll
    for (int j = 0; j < NF; ++j) memr[i][j] = 0.0f;

  // ---- stage the ENTIRE panel once (global -> reg -> swizzled ds_write) ----
#pragma unroll
  for (int kt = 0; kt < NK; ++kt) {
    f16* T = Bsm + kt * TILE;
    if constexpr (NF == 2) {
      // 64-row tile: hi rows 0..31 (col=r), lo rows 32..63; 2 writes/thread
      const int r = lrow;
      const f16* src = Wc + (size_t)(n0 + r) * K2 + kt * 64 + lk;
      const short8 vh = *(const short8*)(src);
      const short8 vl = *(const short8*)(src + K);
      const int sw = lk ^ ((r & 7) << 3);
      *(short8*)(T + r * 64 + sw) = vh;
      *(short8*)(T + (32 + r) * 64 + sw) = vl;  // (32+r)&7 == r&7
    } else {
      // 32-row tile: hi rows 0..15 (col=r), lo rows 16..31 (col=r-16)
      const int r = lrow;
      const int c = r & 15;
      const f16* src =
          Wc + (size_t)(n0 + c) * K2 + ((r < 16) ? 0 : K) + kt * 64 + lk;
      const short8 v = *(const short8*)(src);
      const int sw = lk ^ ((r & 7) << 3);
      *(short8*)(T + r * 64 + sw) = v;
    }
  }
  __syncthreads();  // the ONLY barrier

  const f16* Acur = A_all + (size_t)(m0 + wm * 32 + (lane & 15)) * K +
                    ((lane >> 4) * 8);
  const size_t Astep = (size_t)B_TOTAL * K;

  const int col = lane & 15;
  const int rbase = (lane >> 4) * 4;

  for (int st = 0; st < 25; ++st) {
#pragma unroll
    for (int i = 0; i < 2; ++i)
#pragma unroll
      for (int j = 0; j < NF; ++j) {
        acch[i][j] = 0.0f;
        accl[i][j] = 0.0f;
      }

#pragma unroll
    for (int kt = 0; kt < NK; ++kt) {
      const f16* T = Bsm + kt * TILE;
      const f16* At = Acur + kt * 64;
#pragma unroll
      for (int ks = 0; ks < 64; ks += 32) {
        const int kb = ks + (lane >> 4) * 8;
        half8 af[2], bh[NF], bl[NF];
#pragma unroll
        for (int i = 0; i < 2; ++i)
          af[i] = *(const half8*)(At + (size_t)i * 16 * K + ks);
#pragma unroll
        for (int j = 0; j < NF; ++j) {
          const int rh = j * 16 + col;
          const int rl = 16 * NF + rh;
          bh[j] = *(const half8*)(T + rh * 64 + (kb ^ ((rh & 7) << 3)));
          bl[j] = *(const half8*)(T + rl * 64 + (kb ^ ((rl & 7) << 3)));
        }
#pragma unroll
        for (int i = 0; i < 2; ++i)
#pragma unroll
          for (int j = 0; j < NF; ++j) {
            acch[i][j] = __builtin_amdgcn_mfma_f32_16x16x32_f16(
                af[i], bh[j], acch[i][j], 0, 0, 0);
            accl[i][j] = __builtin_amdgcn_mfma_f32_16x16x32_f16(
                af[i], bl[j], accl[i][j], 0, 0, 0);
          }
      }
    }

    // epilogue: combine hi/lo, bias+relu, LIF update, store
#pragma unroll
    for (int i = 0; i < 2; ++i) {
#pragma unroll
      for (int r = 0; r < 4; ++r) {
        const int m = m0 + wm * 32 + i * 16 + rbase + r;
#pragma unroll
        for (int j = 0; j < NF; ++j) {
          const int n = n0 + j * 16 + col;
          const float v =
              __fadd_rn(acch[i][j][r], __fmul_rn(accl[i][j][r], LO_SCALE));
          float cur = __fadd_rn(__fmul_rn(v, ACC_SCALE), bias_r[j]);
          cur = cur > 0.0f ? cur : 0.0f;
          const float mo = memr[i][j][r];
          const float reset = (mo - 1.0f > 0.0f) ? 1.0f : 0.0f;
          float mn = __fmul_rn(0.95f, mo);
          mn = __fadd_rn(mn, cur);
          mn = __fsub_rn(mn, reset);
          memr[i][j][r] = mn;
          const float s = (mn - 1.0f > 0.0f) ? 1.0f : 0.0f;
          const size_t idx =
              (size_t)st * (B_TOTAL * (size_t)N) + (size_t)m * N + n;
          if (mode == 1) {
            sr[idx] = s;
            mr[idx] = tanhf(mn);
          } else {
            spk_out[idx] = (f16)s;
          }
        }
      }
    }
    Acur += Astep;
  }
}

// ---------------------------------------------------------------------------
extern "C" void kernel_launch(void* const* d_in, const int* in_sizes, int n_in,
                              void* d_out, int out_size, void* d_ws,
                              size_t ws_size, hipStream_t stream) {
  const float* x = (const float*)d_in[0];
  const float* W[5];
  const float* bi[5];
  for (int i = 0; i < 5; ++i) {
    W[i] = (const float*)d_in[1 + 2 * i];
    bi[i] = (const float*)d_in[2 + 2 * i];
  }

  const int B = B_TOTAL;
  const int Ns[5] = {128, 256, 512, 1024, 784};
  const int Ks[5] = {100, 128, 256, 512, 1024};

  char* ws = (char*)d_ws;
  size_t off = 0;
  auto alloc = [&](size_t bytes) {
    void* p = ws + off;
    off = (off + bytes + 255) & ~(size_t)255;
    return p;
  };

  float* cur1 = (float*)alloc((size_t)B * 128 * 4);
  // all-step spike buffers: s{l}[25][B][N_l] f16
  f16* s1 = (f16*)alloc((size_t)25 * B * 128 * 2);
  f16* s2 = (f16*)alloc((size_t)25 * B * 256 * 2);
  f16* s3 = (f16*)alloc((size_t)25 * B * 512 * 2);
  f16* s4 = (f16*)alloc((size_t)25 * B * 1024 * 2);
  f16* Wc[5];
  for (int i = 1; i < 5; ++i)
    Wc[i] = (f16*)alloc((size_t)Ns[i] * Ks[i] * 2 * 2);

  float* outF = (float*)d_out;
  float* spk_rec = outF;
  float* mem_rec = outF + (size_t)25 * B * 784;

  // 2-split weights for layers 2..5
  for (int i = 1; i < 5; ++i) {
    const int total = Ns[i] * Ks[i];
    split2_kernel<<<(total + 255) / 256, 256, 0, stream>>>(W[i], Wc[i], total,
                                                           Ks[i]);
  }

  // layer-1 current: relu(x @ W1^T + b1), computed once (x is step-invariant)
  gemm_relu_f32_kernel<<<dim3(2, B / 64), 256, 0, stream>>>(x, W[0], bi[0],
                                                            cur1, 128, 100);

  // layer-1 LIF: full 25-step recurrence (cur1 fixed, mem in registers)
  lif1_kernel<<<(B * 128) / 1024, 256, 0, stream>>>(cur1, s1);

  // layers 2..5: one kernel each, 25 steps internal, mem in registers.
  // grid = 16 m-tiles x (N / (16*NF)) n-tiles; LDS = NK*NF*4096 bytes.
  layer_kernel<2, 2><<<16 * 8, 256, 2 * 2 * 4096, stream>>>(
      s1, Wc[1], bi[1], s2, nullptr, nullptr, 256, 128, 0);
  layer_kernel<4, 2><<<16 * 16, 256, 4 * 2 * 4096, stream>>>(
      s2, Wc[2], bi[2], s3, nullptr, nullptr, 512, 256, 0);
  layer_kernel<8, 2><<<16 * 32, 256, 8 * 2 * 4096, stream>>>(
      s3, Wc[3], bi[3], s4, nullptr, nullptr, 1024, 512, 0);
  layer_kernel<16, 1><<<16 * 49, 256, 16 * 1 * 4096, stream>>>(
      s4, Wc[4], bi[4], nullptr, spk_rec, mem_rec, 784, 1024, 1);
}

// Round 7
// 1671.283 us; speedup vs baseline: 1.4758x; 1.4758x over previous
//
#include <hip/hip_runtime.h>
#include <math.h>

// SNN: 5 LIF layers, B=2048, dims 100->128->256->512->1024->784, 25 steps.
// Round 14: keep round-13's barrier-free resident-B structure, fix its two
// measured failure modes (L5: 1622us, VGPR 180, MfmaUtil 4%, ~6.4k cyc per
// K-tile = serialized HBM-latency A-loads):
//  (a) A-load ILP: load ALL the K-tile's A fragments (MF*2 dwordx4, batched)
//      BEFORE the MFMAs, and '#pragma unroll 2' (not full) on the kt loop so
//      two tiles' loads are in flight -> latency amortized 8-16x instead of
//      serialized per load. Full NK unroll (round 13) exploded VGPR to 180
//      and the regalloc serialized load-use pairs.
//  (b) L5 geometry MF=4: block 256x16 (4 waves = 64-row m-strips), m-tiles=8
//      -> exactly ONE A-slice per XCD (512KB/step), so step-phase drift
//      between unsynchronized blocks stays L2-resident (round 13 had 2
//      slices/XCD x drift -> L2 thrash -> HBM-latency loads). 49 n-blocks
//      per XCD reuse that slice. MFMA:A-load back to 2:1, acc = 32 VGPR.
// L4/L3/L2: NF=2, MF=2 (2 slices/XCD within drift window), same batched
// compute body. Numerics bit-identical (same K-order / op chain).

typedef _Float16 f16;
typedef __attribute__((ext_vector_type(8))) short short8;
typedef __attribute__((ext_vector_type(8))) _Float16 half8;
typedef __attribute__((ext_vector_type(4))) _Float16 half4;
typedef __attribute__((ext_vector_type(4))) float f32x4;

#define B_TOTAL 2048
#define LO_SCALE 2.44140625e-4f  // 2^-12, undoes the lo x2^12 storage scale
#define ACC_SCALE 0.015625f      // 2^-6, undoes the x64 weight pre-scale

// ---------- fp32 64x64 GEMM + relu (layer-1 current, runs once) ------------
__global__ __launch_bounds__(256) void gemm_relu_f32_kernel(
    const float* __restrict__ h, const float* __restrict__ W,
    const float* __restrict__ bias, float* __restrict__ out, int N, int K) {
  __shared__ float As[16][64];
  __shared__ float Bs[16][64];

  const int t = threadIdx.x;
  const int tx = t & 15;
  const int ty = t >> 4;
  const int m0 = blockIdx.y * 64;
  const int n0 = blockIdx.x * 64;
  const int lr = t >> 2;
  const int lc = (t & 3) * 4;

  float acc[4][4];
#pragma unroll
  for (int i = 0; i < 4; ++i)
#pragma unroll
    for (int j = 0; j < 4; ++j) acc[i][j] = 0.0f;

  const int ktiles = (K + 15) / 16;
  for (int kt = 0; kt < ktiles; ++kt) {
    const int kbase = kt * 16;
    {
      const float* src = h + (size_t)(m0 + lr) * K + kbase + lc;
#pragma unroll
      for (int j = 0; j < 4; ++j) {
        const int kg = kbase + lc + j;
        As[lc + j][lr] = (kg < K) ? src[j] : 0.0f;
      }
    }
    {
      const int nr = n0 + lr;
      const float* src = W + (size_t)nr * K + kbase + lc;
#pragma unroll
      for (int j = 0; j < 4; ++j) {
        const int kg = kbase + lc + j;
        Bs[lc + j][lr] = (nr < N && kg < K) ? src[j] : 0.0f;
      }
    }
    __syncthreads();
#pragma unroll
    for (int k = 0; k < 16; ++k) {
      float a[4], bb[4];
#pragma unroll
      for (int i = 0; i < 4; ++i) a[i] = As[k][ty * 4 + i];
#pragma unroll
      for (int j = 0; j < 4; ++j) bb[j] = Bs[k][tx * 4 + j];
#pragma unroll
      for (int i = 0; i < 4; ++i)
#pragma unroll
        for (int j = 0; j < 4; ++j) acc[i][j] = fmaf(a[i], bb[j], acc[i][j]);
    }
    __syncthreads();
  }

#pragma unroll
  for (int i = 0; i < 4; ++i) {
    const int m = m0 + ty * 4 + i;
#pragma unroll
    for (int j = 0; j < 4; ++j) {
      const int n = n0 + tx * 4 + j;
      if (n < N) {
        float cur = acc[i][j] + bias[n];
        out[(size_t)m * N + n] = cur > 0.0f ? cur : 0.0f;
      }
    }
  }
}

// ---------- f16 2-split: W fp32 [N,K] -> Wc f16 [N, 2K] = [hi | lo*2^12] ---
__global__ __launch_bounds__(256) void split2_kernel(
    const float* __restrict__ W, f16* __restrict__ Wc, int total, int K) {
  const int idx = blockIdx.x * 256 + threadIdx.x;
  if (idx < total) {
    const int n = idx / K;
    const int k = idx - n * K;
    const float w64 = W[idx] * 64.0f;
    const f16 hi = (f16)w64;
    const float r = w64 - (float)hi;
    const f16 lo = (f16)(r * 4096.0f);
    const size_t base = (size_t)n * 2 * K + k;
    Wc[base] = hi;
    Wc[base + K] = lo;
  }
}

// ---------- lif1: full 25-step recurrence, cur1 is step-invariant ----------
__global__ __launch_bounds__(256) void lif1_kernel(
    const float* __restrict__ cur1, f16* __restrict__ s1_all) {
  const int i0 = (blockIdx.x * 256 + (int)threadIdx.x) * 4;
  const float4 c = *(const float4*)(cur1 + i0);
  const float ca[4] = {c.x, c.y, c.z, c.w};
  float m[4] = {0.0f, 0.0f, 0.0f, 0.0f};
  for (int st = 0; st < 25; ++st) {
    half4 sv;
#pragma unroll
    for (int j = 0; j < 4; ++j) {
      const float mo = m[j];
      const float reset = (mo - 1.0f > 0.0f) ? 1.0f : 0.0f;
      float mn = __fmul_rn(0.95f, mo);
      mn = __fadd_rn(mn, ca[j]);
      mn = __fsub_rn(mn, reset);
      m[j] = mn;
      sv[j] = (f16)((mn - 1.0f > 0.0f) ? 1.0f : 0.0f);
    }
    *(half4*)(s1_all + (size_t)st * (B_TOTAL * 128) + i0) = sv;
  }
}

// ---------- per-layer GEMM + LIF, 25 steps, fully-resident B panel ---------
// Block tile (64*MF) x (16*NF); 4 waves = 4 m-strips of 16*MF rows; wave
// tile (16*MF) x (16*NF) via 16x16x32 MFMA (MF m-frags x NF n-frags, hi+lo).
// LDS: NK swizzled K-64 tiles (32*NF rows x 64 f16), staged ONCE behind a
// single barrier; the 25-step loop is barrier-free. Per K-tile the compute
// body loads ALL MF*2 A fragments (batched dwordx4) before the MFMAs, with
// '#pragma unroll 2' on the kt loop for 2-deep load pipelining.
// mem state lives in registers for all 25 steps.
// XCD mapping: NMT = 2048/(64*MF) m-tiles (8 or 16, both %8==0):
// m-tile = lb%NMT, n-tile = lb/NMT -> XCD = lb%8 = m-tile%8.
template <int NK, int NF, int MF>
__global__ __launch_bounds__(256) void layer_kernel(
    const f16* __restrict__ A_all,   // [25][2048][K] input spikes
    const f16* __restrict__ Wc,      // [N][2K] = [hi | lo]
    const float* __restrict__ bias,
    f16* __restrict__ spk_out,       // [25][2048][N]   (mode 0)
    float* __restrict__ sr, float* __restrict__ mr,  // [25][2048][N] (mode 1)
    int N, int K, int mode) {
  extern __shared__ f16 Bsm[];
  constexpr int TROWS = 32 * NF;    // rows per K-tile (hi block + lo block)
  constexpr int TILE = TROWS * 64;  // f16 per K-tile
  constexpr int MB = 64 * MF;       // block rows
  constexpr int NMT = 2048 / MB;    // m-tiles (16 for MF=2, 8 for MF=4)

  const int t = threadIdx.x;
  const int lane = t & 63;
  const int wm = t >> 6;            // m-strip 0..3
  const int lb = blockIdx.x;
  const int m0 = (lb & (NMT - 1)) * MB;  // XCD = lb%8 = m-tile%8
  const int n0 = (lb / NMT) * (16 * NF);
  const int lrow = t >> 3;          // 0..31 staging row
  const int lk = (t & 7) * 8;       // staging f16 col chunk
  const int K2 = 2 * K;

  // bias per owned column (N is an exact multiple of the n-tile)
  float bias_r[NF];
#pragma unroll
  for (int j = 0; j < NF; ++j) bias_r[j] = bias[n0 + j * 16 + (lane & 15)];

  // accumulators + membrane state (registers, persistent across 25 steps)
  f32x4 acch[MF][NF], accl[MF][NF], memr[MF][NF];
#pragma unroll
  for (int i = 0; i < MF; ++i)
#pragma unroll
    for (int j = 0; j < NF; ++j) memr[i][j] = 0.0f;

  // ---- stage the ENTIRE panel once (global -> reg -> swizzled ds_write) ----
#pragma unroll
  for (int kt = 0; kt < NK; ++kt) {
    f16* T = Bsm + kt * TILE;
    if constexpr (NF == 2) {
      // 64-row tile: hi rows 0..31 (col=r), lo rows 32..63
      const int r = lrow;
      const f16* src = Wc + (size_t)(n0 + r) * K2 + kt * 64 + lk;
      const short8 vh = *(const short8*)(src);
      const short8 vl = *(const short8*)(src + K);
      const int sw = lk ^ ((r & 7) << 3);
      *(short8*)(T + r * 64 + sw) = vh;
      *(short8*)(T + (32 + r) * 64 + sw) = vl;  // (32+r)&7 == r&7
    } else {
      // 32-row tile: hi rows 0..15 (col=r), lo rows 16..31 (col=r-16)
      const int r = lrow;
      const int c = r & 15;
      const f16* src =
          Wc + (size_t)(n0 + c) * K2 + ((r < 16) ? 0 : K) + kt * 64 + lk;
      const short8 v = *(const short8*)(src);
      const int sw = lk ^ ((r & 7) << 3);
      *(short8*)(T + r * 64 + sw) = v;
    }
  }
  __syncthreads();  // the ONLY barrier

  const f16* Acur = A_all + (size_t)(m0 + wm * (16 * MF) + (lane & 15)) * K +
                    ((lane >> 4) * 8);
  const size_t Astep = (size_t)B_TOTAL * K;

  const int col = lane & 15;
  const int rbase = (lane >> 4) * 4;

  for (int st = 0; st < 25; ++st) {
#pragma unroll
    for (int i = 0; i < MF; ++i)
#pragma unroll
      for (int j = 0; j < NF; ++j) {
        acch[i][j] = 0.0f;
        accl[i][j] = 0.0f;
      }

#pragma unroll 2
    for (int kt = 0; kt < NK; ++kt) {
      const f16* T = Bsm + kt * TILE;
      const f16* At = Acur + kt * 64;
      // batch ALL the tile's A-fragment loads before any MFMA
      half8 af[MF][2];
#pragma unroll
      for (int i = 0; i < MF; ++i)
#pragma unroll
        for (int s = 0; s < 2; ++s)
          af[i][s] = *(const half8*)(At + (size_t)i * 16 * K + s * 32);
#pragma unroll
      for (int s = 0; s < 2; ++s) {
        const int kb = s * 32 + (lane >> 4) * 8;
        half8 bh[NF], bl[NF];
#pragma unroll
        for (int j = 0; j < NF; ++j) {
          const int rh = j * 16 + col;
          const int rl = 16 * NF + rh;
          bh[j] = *(const half8*)(T + rh * 64 + (kb ^ ((rh & 7) << 3)));
          bl[j] = *(const half8*)(T + rl * 64 + (kb ^ ((rl & 7) << 3)));
        }
#pragma unroll
        for (int i = 0; i < MF; ++i)
#pragma unroll
          for (int j = 0; j < NF; ++j) {
            acch[i][j] = __builtin_amdgcn_mfma_f32_16x16x32_f16(
                af[i][s], bh[j], acch[i][j], 0, 0, 0);
            accl[i][j] = __builtin_amdgcn_mfma_f32_16x16x32_f16(
                af[i][s], bl[j], accl[i][j], 0, 0, 0);
          }
      }
    }

    // epilogue: combine hi/lo, bias+relu, LIF update, store
#pragma unroll
    for (int i = 0; i < MF; ++i) {
#pragma unroll
      for (int r = 0; r < 4; ++r) {
        const int m = m0 + wm * (16 * MF) + i * 16 + rbase + r;
#pragma unroll
        for (int j = 0; j < NF; ++j) {
          const int n = n0 + j * 16 + col;
          const float v =
              __fadd_rn(acch[i][j][r], __fmul_rn(accl[i][j][r], LO_SCALE));
          float cur = __fadd_rn(__fmul_rn(v, ACC_SCALE), bias_r[j]);
          cur = cur > 0.0f ? cur : 0.0f;
          const float mo = memr[i][j][r];
          const float reset = (mo - 1.0f > 0.0f) ? 1.0f : 0.0f;
          float mn = __fmul_rn(0.95f, mo);
          mn = __fadd_rn(mn, cur);
          mn = __fsub_rn(mn, reset);
          memr[i][j][r] = mn;
          const float s = (mn - 1.0f > 0.0f) ? 1.0f : 0.0f;
          const size_t idx =
              (size_t)st * (B_TOTAL * (size_t)N) + (size_t)m * N + n;
          if (mode == 1) {
            sr[idx] = s;
            mr[idx] = tanhf(mn);
          } else {
            spk_out[idx] = (f16)s;
          }
        }
      }
    }
    Acur += Astep;
  }
}

// ---------------------------------------------------------------------------
extern "C" void kernel_launch(void* const* d_in, const int* in_sizes, int n_in,
                              void* d_out, int out_size, void* d_ws,
                              size_t ws_size, hipStream_t stream) {
  const float* x = (const float*)d_in[0];
  const float* W[5];
  const float* bi[5];
  for (int i = 0; i < 5; ++i) {
    W[i] = (const float*)d_in[1 + 2 * i];
    bi[i] = (const float*)d_in[2 + 2 * i];
  }

  const int B = B_TOTAL;
  const int Ns[5] = {128, 256, 512, 1024, 784};
  const int Ks[5] = {100, 128, 256, 512, 1024};

  char* ws = (char*)d_ws;
  size_t off = 0;
  auto alloc = [&](size_t bytes) {
    void* p = ws + off;
    off = (off + bytes + 255) & ~(size_t)255;
    return p;
  };

  float* cur1 = (float*)alloc((size_t)B * 128 * 4);
  // all-step spike buffers: s{l}[25][B][N_l] f16
  f16* s1 = (f16*)alloc((size_t)25 * B * 128 * 2);
  f16* s2 = (f16*)alloc((size_t)25 * B * 256 * 2);
  f16* s3 = (f16*)alloc((size_t)25 * B * 512 * 2);
  f16* s4 = (f16*)alloc((size_t)25 * B * 1024 * 2);
  f16* Wc[5];
  for (int i = 1; i < 5; ++i)
    Wc[i] = (f16*)alloc((size_t)Ns[i] * Ks[i] * 2 * 2);

  float* outF = (float*)d_out;
  float* spk_rec = outF;
  float* mem_rec = outF + (size_t)25 * B * 784;

  // 2-split weights for layers 2..5
  for (int i = 1; i < 5; ++i) {
    const int total = Ns[i] * Ks[i];
    split2_kernel<<<(total + 255) / 256, 256, 0, stream>>>(W[i], Wc[i], total,
                                                           Ks[i]);
  }

  // layer-1 current: relu(x @ W1^T + b1), computed once (x is step-invariant)
  gemm_relu_f32_kernel<<<dim3(2, B / 64), 256, 0, stream>>>(x, W[0], bi[0],
                                                            cur1, 128, 100);

  // layer-1 LIF: full 25-step recurrence (cur1 fixed, mem in registers)
  lif1_kernel<<<(B * 128) / 1024, 256, 0, stream>>>(cur1, s1);

  // layers 2..5: one kernel each, 25 steps internal, mem in registers.
  // grid = NMT m-tiles x (N/(16*NF)) n-tiles; LDS = NK*NF*4096 bytes.
  layer_kernel<2, 2, 2><<<16 * 8, 256, 2 * 2 * 4096, stream>>>(
      s1, Wc[1], bi[1], s2, nullptr, nullptr, 256, 128, 0);
  layer_kernel<4, 2, 2><<<16 * 16, 256, 4 * 2 * 4096, stream>>>(
      s2, Wc[2], bi[2], s3, nullptr, nullptr, 512, 256, 0);
  layer_kernel<8, 2, 2><<<16 * 32, 256, 8 * 2 * 4096, stream>>>(
      s3, Wc[3], bi[3], s4, nullptr, nullptr, 1024, 512, 0);
  layer_kernel<16, 1, 4><<<8 * 49, 256, 16 * 1 * 4096, stream>>>(
      s4, Wc[4], bi[4], nullptr, spk_rec, mem_rec, 784, 1024, 1);
}

// Round 8
// 1362.983 us; speedup vs baseline: 1.8097x; 1.2262x over previous
//
#include <hip/hip_runtime.h>
#include <math.h>

// SNN: 5 LIF layers, B=2048, dims 100->128->256->512->1024->784, 25 steps.
// Round 15: keep round-14's resident-B barrier-free structure and geometry
// (XCD mapping verified: FETCH 64MB < A panel). Round-14 counters showed
// everything idle (Mfma 6.4%, VALU 7.4%, HBM 4.7%) at ~3000 cyc/K-tile vs
// ~260 cyc of work: pure exposed load latency -- each tile does
// {issue 8 A-loads, wait vmcnt(0), 16 MFMA} with only 2 blocks/CU to
// cross-cover, and 13->14 showed time scales ~1/overlap-depth.
// Single change: explicit DEPTH-2 REGISTER PREFETCH across the flat
// (step x K-tile) space (barrier-free makes cross-step prefetch legal):
//   body(it,it+1): load(it+2)->nx; mfma(cx); load(it+3)->ny; mfma(cy);
//                  [epilogue if step complete]; cx=nx; cy=ny;
// Loads are consumed one body (~800cyc) after issue -> latency hidden.
// Peak live = 3 tile buffers (~96 VGPR) + acc/mem (~64) ~= 190 VGPR: fine,
// occupancy is LDS-bound (2 blocks/CU) regardless.
// Numerics bit-identical (same per-element K-order / op chain).

typedef _Float16 f16;
typedef __attribute__((ext_vector_type(8))) short short8;
typedef __attribute__((ext_vector_type(8))) _Float16 half8;
typedef __attribute__((ext_vector_type(4))) _Float16 half4;
typedef __attribute__((ext_vector_type(4))) float f32x4;

#define B_TOTAL 2048
#define LO_SCALE 2.44140625e-4f  // 2^-12, undoes the lo x2^12 storage scale
#define ACC_SCALE 0.015625f      // 2^-6, undoes the x64 weight pre-scale

// ---------- fp32 64x64 GEMM + relu (layer-1 current, runs once) ------------
__global__ __launch_bounds__(256) void gemm_relu_f32_kernel(
    const float* __restrict__ h, const float* __restrict__ W,
    const float* __restrict__ bias, float* __restrict__ out, int N, int K) {
  __shared__ float As[16][64];
  __shared__ float Bs[16][64];

  const int t = threadIdx.x;
  const int tx = t & 15;
  const int ty = t >> 4;
  const int m0 = blockIdx.y * 64;
  const int n0 = blockIdx.x * 64;
  const int lr = t >> 2;
  const int lc = (t & 3) * 4;

  float acc[4][4];
#pragma unroll
  for (int i = 0; i < 4; ++i)
#pragma unroll
    for (int j = 0; j < 4; ++j) acc[i][j] = 0.0f;

  const int ktiles = (K + 15) / 16;
  for (int kt = 0; kt < ktiles; ++kt) {
    const int kbase = kt * 16;
    {
      const float* src = h + (size_t)(m0 + lr) * K + kbase + lc;
#pragma unroll
      for (int j = 0; j < 4; ++j) {
        const int kg = kbase + lc + j;
        As[lc + j][lr] = (kg < K) ? src[j] : 0.0f;
      }
    }
    {
      const int nr = n0 + lr;
      const float* src = W + (size_t)nr * K + kbase + lc;
#pragma unroll
      for (int j = 0; j < 4; ++j) {
        const int kg = kbase + lc + j;
        Bs[lc + j][lr] = (nr < N && kg < K) ? src[j] : 0.0f;
      }
    }
    __syncthreads();
#pragma unroll
    for (int k = 0; k < 16; ++k) {
      float a[4], bb[4];
#pragma unroll
      for (int i = 0; i < 4; ++i) a[i] = As[k][ty * 4 + i];
#pragma unroll
      for (int j = 0; j < 4; ++j) bb[j] = Bs[k][tx * 4 + j];
#pragma unroll
      for (int i = 0; i < 4; ++i)
#pragma unroll
        for (int j = 0; j < 4; ++j) acc[i][j] = fmaf(a[i], bb[j], acc[i][j]);
    }
    __syncthreads();
  }

#pragma unroll
  for (int i = 0; i < 4; ++i) {
    const int m = m0 + ty * 4 + i;
#pragma unroll
    for (int j = 0; j < 4; ++j) {
      const int n = n0 + tx * 4 + j;
      if (n < N) {
        float cur = acc[i][j] + bias[n];
        out[(size_t)m * N + n] = cur > 0.0f ? cur : 0.0f;
      }
    }
  }
}

// ---------- f16 2-split: W fp32 [N,K] -> Wc f16 [N, 2K] = [hi | lo*2^12] ---
__global__ __launch_bounds__(256) void split2_kernel(
    const float* __restrict__ W, f16* __restrict__ Wc, int total, int K) {
  const int idx = blockIdx.x * 256 + threadIdx.x;
  if (idx < total) {
    const int n = idx / K;
    const int k = idx - n * K;
    const float w64 = W[idx] * 64.0f;
    const f16 hi = (f16)w64;
    const float r = w64 - (float)hi;
    const f16 lo = (f16)(r * 4096.0f);
    const size_t base = (size_t)n * 2 * K + k;
    Wc[base] = hi;
    Wc[base + K] = lo;
  }
}

// ---------- lif1: full 25-step recurrence, cur1 is step-invariant ----------
__global__ __launch_bounds__(256) void lif1_kernel(
    const float* __restrict__ cur1, f16* __restrict__ s1_all) {
  const int i0 = (blockIdx.x * 256 + (int)threadIdx.x) * 4;
  const float4 c = *(const float4*)(cur1 + i0);
  const float ca[4] = {c.x, c.y, c.z, c.w};
  float m[4] = {0.0f, 0.0f, 0.0f, 0.0f};
  for (int st = 0; st < 25; ++st) {
    half4 sv;
#pragma unroll
    for (int j = 0; j < 4; ++j) {
      const float mo = m[j];
      const float reset = (mo - 1.0f > 0.0f) ? 1.0f : 0.0f;
      float mn = __fmul_rn(0.95f, mo);
      mn = __fadd_rn(mn, ca[j]);
      mn = __fsub_rn(mn, reset);
      m[j] = mn;
      sv[j] = (f16)((mn - 1.0f > 0.0f) ? 1.0f : 0.0f);
    }
    *(half4*)(s1_all + (size_t)st * (B_TOTAL * 128) + i0) = sv;
  }
}

// ---------- per-layer GEMM + LIF, 25 steps, fully-resident B panel ---------
// Block tile (64*MF) x (16*NF); 4 waves = 4 m-strips of 16*MF rows; wave
// tile (16*MF) x (16*NF) via 16x16x32 MFMA (MF m-frags x NF n-frags, hi+lo).
// LDS: NK swizzled K-64 tiles (32*NF rows x 64 f16), staged ONCE behind a
// single barrier; the 25-step loop is barrier-free. The flat iteration
// space it = st*NK + kt is walked in pairs with a depth-2 register
// prefetch pipeline (loads for it+2/it+3 issued before computing it/it+1),
// crossing step boundaries freely. mem state in registers for all 25 steps.
// XCD mapping: NMT = 2048/(64*MF) m-tiles (8 or 16, both %8==0):
// m-tile = lb%NMT, n-tile = lb/NMT -> XCD = lb%8 = m-tile%8.
template <int NK, int NF, int MF>
__global__ __launch_bounds__(256) void layer_kernel(
    const f16* __restrict__ A_all,   // [25][2048][K] input spikes
    const f16* __restrict__ Wc,      // [N][2K] = [hi | lo]
    const float* __restrict__ bias,
    f16* __restrict__ spk_out,       // [25][2048][N]   (mode 0)
    float* __restrict__ sr, float* __restrict__ mr,  // [25][2048][N] (mode 1)
    int N, int K, int mode) {
  extern __shared__ f16 Bsm[];
  constexpr int TROWS = 32 * NF;    // rows per K-tile (hi block + lo block)
  constexpr int TILE = TROWS * 64;  // f16 per K-tile
  constexpr int MB = 64 * MF;       // block rows
  constexpr int NMT = 2048 / MB;    // m-tiles (16 for MF=2, 8 for MF=4)
  constexpr int LOG_NK = (NK == 2) ? 1 : (NK == 4) ? 2 : (NK == 8) ? 3 : 4;
  constexpr int TOT = 25 * NK;      // flat iteration count (even)

  const int t = threadIdx.x;
  const int lane = t & 63;
  const int wm = t >> 6;            // m-strip 0..3
  const int lb = blockIdx.x;
  const int m0 = (lb & (NMT - 1)) * MB;  // XCD = lb%8 = m-tile%8
  const int n0 = (lb / NMT) * (16 * NF);
  const int lrow = t >> 3;          // 0..31 staging row
  const int lk = (t & 7) * 8;       // staging f16 col chunk
  const int K2 = 2 * K;

  // bias per owned column (N is an exact multiple of the n-tile)
  float bias_r[NF];
#pragma unroll
  for (int j = 0; j < NF; ++j) bias_r[j] = bias[n0 + j * 16 + (lane & 15)];

  // accumulators + membrane state (registers, persistent across 25 steps)
  f32x4 acch[MF][NF], accl[MF][NF], memr[MF][NF];
#pragma unroll
  for (int i = 0; i < MF; ++i)
#pragma unroll
    for (int j = 0; j < NF; ++j) memr[i][j] = 0.0f;

  // ---- stage the ENTIRE panel once (global -> reg -> swizzled ds_write) ----
#pragma unroll
  for (int kt = 0; kt < NK; ++kt) {
    f16* T = Bsm + kt * TILE;
    if constexpr (NF == 2) {
      // 64-row tile: hi rows 0..31 (col=r), lo rows 32..63
      const int r = lrow;
      const f16* src = Wc + (size_t)(n0 + r) * K2 + kt * 64 + lk;
      const short8 vh = *(const short8*)(src);
      const short8 vl = *(const short8*)(src + K);
      const int sw = lk ^ ((r & 7) << 3);
      *(short8*)(T + r * 64 + sw) = vh;
      *(short8*)(T + (32 + r) * 64 + sw) = vl;  // (32+r)&7 == r&7
    } else {
      // 32-row tile: hi rows 0..15 (col=r), lo rows 16..31 (col=r-16)
      const int r = lrow;
      const int c = r & 15;
      const f16* src =
          Wc + (size_t)(n0 + c) * K2 + ((r < 16) ? 0 : K) + kt * 64 + lk;
      const short8 v = *(const short8*)(src);
      const int sw = lk ^ ((r & 7) << 3);
      *(short8*)(T + r * 64 + sw) = v;
    }
  }
  __syncthreads();  // the ONLY barrier

  const f16* Abase = A_all + (size_t)(m0 + wm * (16 * MF) + (lane & 15)) * K +
                     ((lane >> 4) * 8);
  const size_t Astep = (size_t)B_TOTAL * K;

  const int col = lane & 15;
  const int rbase = (lane >> 4) * 4;

  // load all MF*2 A fragments of flat tile j into buf
  auto load_tile = [&](int j, half8 (&buf)[MF][2]) {
    const f16* At =
        Abase + (size_t)(j >> LOG_NK) * Astep + (j & (NK - 1)) * 64;
#pragma unroll
    for (int i = 0; i < MF; ++i)
#pragma unroll
      for (int s = 0; s < 2; ++s)
        buf[i][s] = *(const half8*)(At + (size_t)i * 16 * K + s * 32);
  };

  // consume flat tile j's A fragments against the LDS-resident B tile
  auto compute_tile = [&](int j, const half8 (&buf)[MF][2]) {
    const f16* T = Bsm + (j & (NK - 1)) * TILE;
#pragma unroll
    for (int s = 0; s < 2; ++s) {
      const int kb = s * 32 + (lane >> 4) * 8;
      half8 bh[NF], bl[NF];
#pragma unroll
      for (int jj = 0; jj < NF; ++jj) {
        const int rh = jj * 16 + col;
        const int rl = 16 * NF + rh;
        bh[jj] = *(const half8*)(T + rh * 64 + (kb ^ ((rh & 7) << 3)));
        bl[jj] = *(const half8*)(T + rl * 64 + (kb ^ ((rl & 7) << 3)));
      }
#pragma unroll
      for (int i = 0; i < MF; ++i)
#pragma unroll
        for (int jj = 0; jj < NF; ++jj) {
          acch[i][jj] = __builtin_amdgcn_mfma_f32_16x16x32_f16(
              buf[i][s], bh[jj], acch[i][jj], 0, 0, 0);
          accl[i][jj] = __builtin_amdgcn_mfma_f32_16x16x32_f16(
              buf[i][s], bl[jj], accl[i][jj], 0, 0, 0);
        }
    }
  };

  // epilogue: combine hi/lo, bias+relu, LIF update, store, zero accs
  auto epilogue = [&](int st) {
#pragma unroll
    for (int i = 0; i < MF; ++i) {
#pragma unroll
      for (int r = 0; r < 4; ++r) {
        const int m = m0 + wm * (16 * MF) + i * 16 + rbase + r;
#pragma unroll
        for (int j = 0; j < NF; ++j) {
          const int n = n0 + j * 16 + col;
          const float v =
              __fadd_rn(acch[i][j][r], __fmul_rn(accl[i][j][r], LO_SCALE));
          float cur = __fadd_rn(__fmul_rn(v, ACC_SCALE), bias_r[j]);
          cur = cur > 0.0f ? cur : 0.0f;
          const float mo = memr[i][j][r];
          const float reset = (mo - 1.0f > 0.0f) ? 1.0f : 0.0f;
          float mn = __fmul_rn(0.95f, mo);
          mn = __fadd_rn(mn, cur);
          mn = __fsub_rn(mn, reset);
          memr[i][j][r] = mn;
          const float s = (mn - 1.0f > 0.0f) ? 1.0f : 0.0f;
          const size_t idx =
              (size_t)st * (B_TOTAL * (size_t)N) + (size_t)m * N + n;
          if (mode == 1) {
            sr[idx] = s;
            mr[idx] = tanhf(mn);
          } else {
            spk_out[idx] = (f16)s;
          }
        }
      }
    }
#pragma unroll
    for (int i = 0; i < MF; ++i)
#pragma unroll
      for (int j = 0; j < NF; ++j) {
        acch[i][j] = 0.0f;
        accl[i][j] = 0.0f;
      }
  };

#pragma unroll
  for (int i = 0; i < MF; ++i)
#pragma unroll
    for (int j = 0; j < NF; ++j) {
      acch[i][j] = 0.0f;
      accl[i][j] = 0.0f;
    }

  // ---- depth-2 prefetch pipeline over the flat (step x K-tile) space ----
  half8 cx[MF][2] = {}, cy[MF][2] = {}, nx[MF][2] = {}, ny[MF][2] = {};
  load_tile(0, cx);
  load_tile(1, cy);
  int st = 0;
  for (int it = 0; it < TOT; it += 2) {
    const bool pf = (it + 2 < TOT);
    if (pf) load_tile(it + 2, nx);
    compute_tile(it, cx);
    if (pf) load_tile(it + 3, ny);
    compute_tile(it + 1, cy);
    if (((it + 1) & (NK - 1)) == NK - 1) {
      epilogue(st);
      ++st;
    }
#pragma unroll
    for (int i = 0; i < MF; ++i)
#pragma unroll
      for (int s = 0; s < 2; ++s) {
        cx[i][s] = nx[i][s];
        cy[i][s] = ny[i][s];
      }
  }
}

// ---------------------------------------------------------------------------
extern "C" void kernel_launch(void* const* d_in, const int* in_sizes, int n_in,
                              void* d_out, int out_size, void* d_ws,
                              size_t ws_size, hipStream_t stream) {
  const float* x = (const float*)d_in[0];
  const float* W[5];
  const float* bi[5];
  for (int i = 0; i < 5; ++i) {
    W[i] = (const float*)d_in[1 + 2 * i];
    bi[i] = (const float*)d_in[2 + 2 * i];
  }

  const int B = B_TOTAL;
  const int Ns[5] = {128, 256, 512, 1024, 784};
  const int Ks[5] = {100, 128, 256, 512, 1024};

  char* ws = (char*)d_ws;
  size_t off = 0;
  auto alloc = [&](size_t bytes) {
    void* p = ws + off;
    off = (off + bytes + 255) & ~(size_t)255;
    return p;
  };

  float* cur1 = (float*)alloc((size_t)B * 128 * 4);
  // all-step spike buffers: s{l}[25][B][N_l] f16
  f16* s1 = (f16*)alloc((size_t)25 * B * 128 * 2);
  f16* s2 = (f16*)alloc((size_t)25 * B * 256 * 2);
  f16* s3 = (f16*)alloc((size_t)25 * B * 512 * 2);
  f16* s4 = (f16*)alloc((size_t)25 * B * 1024 * 2);
  f16* Wc[5];
  for (int i = 1; i < 5; ++i)
    Wc[i] = (f16*)alloc((size_t)Ns[i] * Ks[i] * 2 * 2);

  float* outF = (float*)d_out;
  float* spk_rec = outF;
  float* mem_rec = outF + (size_t)25 * B * 784;

  // 2-split weights for layers 2..5
  for (int i = 1; i < 5; ++i) {
    const int total = Ns[i] * Ks[i];
    split2_kernel<<<(total + 255) / 256, 256, 0, stream>>>(W[i], Wc[i], total,
                                                           Ks[i]);
  }

  // layer-1 current: relu(x @ W1^T + b1), computed once (x is step-invariant)
  gemm_relu_f32_kernel<<<dim3(2, B / 64), 256, 0, stream>>>(x, W[0], bi[0],
                                                            cur1, 128, 100);

  // layer-1 LIF: full 25-step recurrence (cur1 fixed, mem in registers)
  lif1_kernel<<<(B * 128) / 1024, 256, 0, stream>>>(cur1, s1);

  // layers 2..5: one kernel each, 25 steps internal, mem in registers.
  // grid = NMT m-tiles x (N/(16*NF)) n-tiles; LDS = NK*NF*4096 bytes.
  layer_kernel<2, 2, 2><<<16 * 8, 256, 2 * 2 * 4096, stream>>>(
      s1, Wc[1], bi[1], s2, nullptr, nullptr, 256, 128, 0);
  layer_kernel<4, 2, 2><<<16 * 16, 256, 4 * 2 * 4096, stream>>>(
      s2, Wc[2], bi[2], s3, nullptr, nullptr, 512, 256, 0);
  layer_kernel<8, 2, 2><<<16 * 32, 256, 8 * 2 * 4096, stream>>>(
      s3, Wc[3], bi[3], s4, nullptr, nullptr, 1024, 512, 0);
  layer_kernel<16, 1, 4><<<8 * 49, 256, 16 * 1 * 4096, stream>>>(
      s4, Wc[4], bi[4], nullptr, spk_rec, mem_rec, 784, 1024, 1);
}

// Round 9
// 1330.405 us; speedup vs baseline: 1.8540x; 1.0245x over previous
//
#include <hip/hip_runtime.h>
#include <math.h>

// SNN: 5 LIF layers, B=2048, dims 100->128->256->512->1024->784, 25 steps.
// Round 16: round-15's depth-2 prefetch only gained 25% because the buffer
// rotation (cx=nx; cy=ny) is itself a serializing vmcnt wait: the copy
// consumes nx, draining loads issued ~150cyc earlier in the SAME body, so
// the effective prefetch distance collapsed to a fraction of a body and
// every tile still exposed a ~500-900cyc L2/L3 round trip (per-iter 4562
// cyc vs ~250 cyc of work, MfmaUtil 8.7%).
// Single change: COPY-FREE depth-4 static pipeline. Four named buffers
// b0..b3, outer loop unrolled by 4 tiles; each slot does
//   compute(j, bS); load(j+4 -> bS); [epilogue if step-end]
// No register moves -> each buffer's s_waitcnt drains loads issued ~3.75
// slots (~700-1000cyc) earlier with 24 loads still in flight (counted-vmcnt
// pattern in register form). Load issue precedes the epilogue so tanh/LIF
// VALU covers load latency at step ends. VGPR +96 (two extra buffers) stays
// under the 256/2-waves-per-SIMD ceiling; occupancy is LDS-bound anyway.
// Numerics bit-identical (same tile order / K-order / hi-lo op chain).

typedef _Float16 f16;
typedef __attribute__((ext_vector_type(8))) short short8;
typedef __attribute__((ext_vector_type(8))) _Float16 half8;
typedef __attribute__((ext_vector_type(4))) _Float16 half4;
typedef __attribute__((ext_vector_type(4))) float f32x4;

#define B_TOTAL 2048
#define LO_SCALE 2.44140625e-4f  // 2^-12, undoes the lo x2^12 storage scale
#define ACC_SCALE 0.015625f      // 2^-6, undoes the x64 weight pre-scale

// ---------- fp32 64x64 GEMM + relu (layer-1 current, runs once) ------------
__global__ __launch_bounds__(256) void gemm_relu_f32_kernel(
    const float* __restrict__ h, const float* __restrict__ W,
    const float* __restrict__ bias, float* __restrict__ out, int N, int K) {
  __shared__ float As[16][64];
  __shared__ float Bs[16][64];

  const int t = threadIdx.x;
  const int tx = t & 15;
  const int ty = t >> 4;
  const int m0 = blockIdx.y * 64;
  const int n0 = blockIdx.x * 64;
  const int lr = t >> 2;
  const int lc = (t & 3) * 4;

  float acc[4][4];
#pragma unroll
  for (int i = 0; i < 4; ++i)
#pragma unroll
    for (int j = 0; j < 4; ++j) acc[i][j] = 0.0f;

  const int ktiles = (K + 15) / 16;
  for (int kt = 0; kt < ktiles; ++kt) {
    const int kbase = kt * 16;
    {
      const float* src = h + (size_t)(m0 + lr) * K + kbase + lc;
#pragma unroll
      for (int j = 0; j < 4; ++j) {
        const int kg = kbase + lc + j;
        As[lc + j][lr] = (kg < K) ? src[j] : 0.0f;
      }
    }
    {
      const int nr = n0 + lr;
      const float* src = W + (size_t)nr * K + kbase + lc;
#pragma unroll
      for (int j = 0; j < 4; ++j) {
        const int kg = kbase + lc + j;
        Bs[lc + j][lr] = (nr < N && kg < K) ? src[j] : 0.0f;
      }
    }
    __syncthreads();
#pragma unroll
    for (int k = 0; k < 16; ++k) {
      float a[4], bb[4];
#pragma unroll
      for (int i = 0; i < 4; ++i) a[i] = As[k][ty * 4 + i];
#pragma unroll
      for (int j = 0; j < 4; ++j) bb[j] = Bs[k][tx * 4 + j];
#pragma unroll
      for (int i = 0; i < 4; ++i)
#pragma unroll
        for (int j = 0; j < 4; ++j) acc[i][j] = fmaf(a[i], bb[j], acc[i][j]);
    }
    __syncthreads();
  }

#pragma unroll
  for (int i = 0; i < 4; ++i) {
    const int m = m0 + ty * 4 + i;
#pragma unroll
    for (int j = 0; j < 4; ++j) {
      const int n = n0 + tx * 4 + j;
      if (n < N) {
        float cur = acc[i][j] + bias[n];
        out[(size_t)m * N + n] = cur > 0.0f ? cur : 0.0f;
      }
    }
  }
}

// ---------- f16 2-split: W fp32 [N,K] -> Wc f16 [N, 2K] = [hi | lo*2^12] ---
__global__ __launch_bounds__(256) void split2_kernel(
    const float* __restrict__ W, f16* __restrict__ Wc, int total, int K) {
  const int idx = blockIdx.x * 256 + threadIdx.x;
  if (idx < total) {
    const int n = idx / K;
    const int k = idx - n * K;
    const float w64 = W[idx] * 64.0f;
    const f16 hi = (f16)w64;
    const float r = w64 - (float)hi;
    const f16 lo = (f16)(r * 4096.0f);
    const size_t base = (size_t)n * 2 * K + k;
    Wc[base] = hi;
    Wc[base + K] = lo;
  }
}

// ---------- lif1: full 25-step recurrence, cur1 is step-invariant ----------
__global__ __launch_bounds__(256) void lif1_kernel(
    const float* __restrict__ cur1, f16* __restrict__ s1_all) {
  const int i0 = (blockIdx.x * 256 + (int)threadIdx.x) * 4;
  const float4 c = *(const float4*)(cur1 + i0);
  const float ca[4] = {c.x, c.y, c.z, c.w};
  float m[4] = {0.0f, 0.0f, 0.0f, 0.0f};
  for (int st = 0; st < 25; ++st) {
    half4 sv;
#pragma unroll
    for (int j = 0; j < 4; ++j) {
      const float mo = m[j];
      const float reset = (mo - 1.0f > 0.0f) ? 1.0f : 0.0f;
      float mn = __fmul_rn(0.95f, mo);
      mn = __fadd_rn(mn, ca[j]);
      mn = __fsub_rn(mn, reset);
      m[j] = mn;
      sv[j] = (f16)((mn - 1.0f > 0.0f) ? 1.0f : 0.0f);
    }
    *(half4*)(s1_all + (size_t)st * (B_TOTAL * 128) + i0) = sv;
  }
}

// ---------- per-layer GEMM + LIF, 25 steps, fully-resident B panel ---------
// Block tile (64*MF) x (16*NF); 4 waves = 4 m-strips of 16*MF rows; wave
// tile (16*MF) x (16*NF) via 16x16x32 MFMA (MF m-frags x NF n-frags, hi+lo).
// LDS: NK swizzled K-64 tiles (32*NF rows x 64 f16), staged ONCE behind a
// single barrier; the 25-step loop is barrier-free. The flat iteration
// space it = st*NK + kt is walked with a copy-free depth-4 register
// prefetch pipeline (4 static buffers, outer loop unrolled x4), crossing
// step boundaries freely. mem state in registers for all 25 steps.
// XCD mapping: NMT = 2048/(64*MF) m-tiles (8 or 16, both %8==0):
// m-tile = lb%NMT, n-tile = lb/NMT -> XCD = lb%8 = m-tile%8.
template <int NK, int NF, int MF>
__global__ __launch_bounds__(256) void layer_kernel(
    const f16* __restrict__ A_all,   // [25][2048][K] input spikes
    const f16* __restrict__ Wc,      // [N][2K] = [hi | lo]
    const float* __restrict__ bias,
    f16* __restrict__ spk_out,       // [25][2048][N]   (mode 0)
    float* __restrict__ sr, float* __restrict__ mr,  // [25][2048][N] (mode 1)
    int N, int K, int mode) {
  extern __shared__ f16 Bsm[];
  constexpr int TROWS = 32 * NF;    // rows per K-tile (hi block + lo block)
  constexpr int TILE = TROWS * 64;  // f16 per K-tile
  constexpr int MB = 64 * MF;       // block rows
  constexpr int NMT = 2048 / MB;    // m-tiles (16 for MF=2, 8 for MF=4)
  constexpr int LOG_NK = (NK == 2) ? 1 : (NK == 4) ? 2 : (NK == 8) ? 3 : 4;
  constexpr int TOT = 25 * NK;      // flat iteration count
  constexpr int MAIN = TOT & ~3;    // multiple-of-4 prefix

  const int t = threadIdx.x;
  const int lane = t & 63;
  const int wm = t >> 6;            // m-strip 0..3
  const int lb = blockIdx.x;
  const int m0 = (lb & (NMT - 1)) * MB;  // XCD = lb%8 = m-tile%8
  const int n0 = (lb / NMT) * (16 * NF);
  const int lrow = t >> 3;          // 0..31 staging row
  const int lk = (t & 7) * 8;       // staging f16 col chunk
  const int K2 = 2 * K;

  // bias per owned column (N is an exact multiple of the n-tile)
  float bias_r[NF];
#pragma unroll
  for (int j = 0; j < NF; ++j) bias_r[j] = bias[n0 + j * 16 + (lane & 15)];

  // accumulators + membrane state (registers, persistent across 25 steps)
  f32x4 acch[MF][NF], accl[MF][NF], memr[MF][NF];
#pragma unroll
  for (int i = 0; i < MF; ++i)
#pragma unroll
    for (int j = 0; j < NF; ++j) memr[i][j] = 0.0f;

  // ---- stage the ENTIRE panel once (global -> reg -> swizzled ds_write) ----
#pragma unroll
  for (int kt = 0; kt < NK; ++kt) {
    f16* T = Bsm + kt * TILE;
    if constexpr (NF == 2) {
      // 64-row tile: hi rows 0..31 (col=r), lo rows 32..63
      const int r = lrow;
      const f16* src = Wc + (size_t)(n0 + r) * K2 + kt * 64 + lk;
      const short8 vh = *(const short8*)(src);
      const short8 vl = *(const short8*)(src + K);
      const int sw = lk ^ ((r & 7) << 3);
      *(short8*)(T + r * 64 + sw) = vh;
      *(short8*)(T + (32 + r) * 64 + sw) = vl;  // (32+r)&7 == r&7
    } else {
      // 32-row tile: hi rows 0..15 (col=r), lo rows 16..31 (col=r-16)
      const int r = lrow;
      const int c = r & 15;
      const f16* src =
          Wc + (size_t)(n0 + c) * K2 + ((r < 16) ? 0 : K) + kt * 64 + lk;
      const short8 v = *(const short8*)(src);
      const int sw = lk ^ ((r & 7) << 3);
      *(short8*)(T + r * 64 + sw) = v;
    }
  }
  __syncthreads();  // the ONLY barrier

  const f16* Abase = A_all + (size_t)(m0 + wm * (16 * MF) + (lane & 15)) * K +
                     ((lane >> 4) * 8);
  const size_t Astep = (size_t)B_TOTAL * K;

  const int col = lane & 15;
  const int rbase = (lane >> 4) * 4;

  // load all MF*2 A fragments of flat tile j into buf
  auto load_tile = [&](int j, half8 (&buf)[MF][2]) {
    const f16* At =
        Abase + (size_t)(j >> LOG_NK) * Astep + (j & (NK - 1)) * 64;
#pragma unroll
    for (int i = 0; i < MF; ++i)
#pragma unroll
      for (int s = 0; s < 2; ++s)
        buf[i][s] = *(const half8*)(At + (size_t)i * 16 * K + s * 32);
  };

  // consume flat tile j's A fragments against the LDS-resident B tile
  auto compute_tile = [&](int j, const half8 (&buf)[MF][2]) {
    const f16* T = Bsm + (j & (NK - 1)) * TILE;
#pragma unroll
    for (int s = 0; s < 2; ++s) {
      const int kb = s * 32 + (lane >> 4) * 8;
      half8 bh[NF], bl[NF];
#pragma unroll
      for (int jj = 0; jj < NF; ++jj) {
        const int rh = jj * 16 + col;
        const int rl = 16 * NF + rh;
        bh[jj] = *(const half8*)(T + rh * 64 + (kb ^ ((rh & 7) << 3)));
        bl[jj] = *(const half8*)(T + rl * 64 + (kb ^ ((rl & 7) << 3)));
      }
#pragma unroll
      for (int i = 0; i < MF; ++i)
#pragma unroll
        for (int jj = 0; jj < NF; ++jj) {
          acch[i][jj] = __builtin_amdgcn_mfma_f32_16x16x32_f16(
              buf[i][s], bh[jj], acch[i][jj], 0, 0, 0);
          accl[i][jj] = __builtin_amdgcn_mfma_f32_16x16x32_f16(
              buf[i][s], bl[jj], accl[i][jj], 0, 0, 0);
        }
    }
  };

  // epilogue: combine hi/lo, bias+relu, LIF update, store, zero accs
  auto epilogue = [&](int st) {
#pragma unroll
    for (int i = 0; i < MF; ++i) {
#pragma unroll
      for (int r = 0; r < 4; ++r) {
        const int m = m0 + wm * (16 * MF) + i * 16 + rbase + r;
#pragma unroll
        for (int j = 0; j < NF; ++j) {
          const int n = n0 + j * 16 + col;
          const float v =
              __fadd_rn(acch[i][j][r], __fmul_rn(accl[i][j][r], LO_SCALE));
          float cur = __fadd_rn(__fmul_rn(v, ACC_SCALE), bias_r[j]);
          cur = cur > 0.0f ? cur : 0.0f;
          const float mo = memr[i][j][r];
          const float reset = (mo - 1.0f > 0.0f) ? 1.0f : 0.0f;
          float mn = __fmul_rn(0.95f, mo);
          mn = __fadd_rn(mn, cur);
          mn = __fsub_rn(mn, reset);
          memr[i][j][r] = mn;
          const float s = (mn - 1.0f > 0.0f) ? 1.0f : 0.0f;
          const size_t idx =
              (size_t)st * (B_TOTAL * (size_t)N) + (size_t)m * N + n;
          if (mode == 1) {
            sr[idx] = s;
            mr[idx] = tanhf(mn);
          } else {
            spk_out[idx] = (f16)s;
          }
        }
      }
    }
#pragma unroll
    for (int i = 0; i < MF; ++i)
#pragma unroll
      for (int j = 0; j < NF; ++j) {
        acch[i][j] = 0.0f;
        accl[i][j] = 0.0f;
      }
  };

#pragma unroll
  for (int i = 0; i < MF; ++i)
#pragma unroll
    for (int j = 0; j < NF; ++j) {
      acch[i][j] = 0.0f;
      accl[i][j] = 0.0f;
    }

  // ---- copy-free depth-4 prefetch pipeline over the flat space ----
  // b0..b3 hold tiles j..j+3 (j = body base, j % 4 == 0). Each slot:
  // compute its tile, immediately re-fill its buffer with tile+4 (consumed
  // ~3.75 slots later), then run the step epilogue if the step completed
  // (load issue precedes epilogue so tanh/LIF VALU covers the latency).
  half8 b0[MF][2], b1[MF][2], b2[MF][2], b3[MF][2];
  load_tile(0, b0);
  load_tile(1, b1);
  load_tile(2, b2);
  load_tile(3, b3);
  int st = 0;
  for (int j = 0; j < MAIN; j += 4) {
    compute_tile(j, b0);
    if (j + 4 < TOT) load_tile(j + 4, b0);
    if (((j + 1) & (NK - 1)) == 0) { epilogue(st); ++st; }
    compute_tile(j + 1, b1);
    if (j + 5 < TOT) load_tile(j + 5, b1);
    if (((j + 2) & (NK - 1)) == 0) { epilogue(st); ++st; }
    compute_tile(j + 2, b2);
    if (j + 6 < TOT) load_tile(j + 6, b2);
    if (((j + 3) & (NK - 1)) == 0) { epilogue(st); ++st; }
    compute_tile(j + 3, b3);
    if (j + 7 < TOT) load_tile(j + 7, b3);
    if (((j + 4) & (NK - 1)) == 0) { epilogue(st); ++st; }
  }
  if constexpr ((TOT & 3) != 0) {
    // only NK=2 (TOT=50): tiles MAIN, MAIN+1 already resident in b0, b1
    compute_tile(MAIN, b0);
    compute_tile(MAIN + 1, b1);
    epilogue(st);
  }
}

// ---------------------------------------------------------------------------
extern "C" void kernel_launch(void* const* d_in, const int* in_sizes, int n_in,
                              void* d_out, int out_size, void* d_ws,
                              size_t ws_size, hipStream_t stream) {
  const float* x = (const float*)d_in[0];
  const float* W[5];
  const float* bi[5];
  for (int i = 0; i < 5; ++i) {
    W[i] = (const float*)d_in[1 + 2 * i];
    bi[i] = (const float*)d_in[2 + 2 * i];
  }

  const int B = B_TOTAL;
  const int Ns[5] = {128, 256, 512, 1024, 784};
  const int Ks[5] = {100, 128, 256, 512, 1024};

  char* ws = (char*)d_ws;
  size_t off = 0;
  auto alloc = [&](size_t bytes) {
    void* p = ws + off;
    off = (off + bytes + 255) & ~(size_t)255;
    return p;
  };

  float* cur1 = (float*)alloc((size_t)B * 128 * 4);
  // all-step spike buffers: s{l}[25][B][N_l] f16
  f16* s1 = (f16*)alloc((size_t)25 * B * 128 * 2);
  f16* s2 = (f16*)alloc((size_t)25 * B * 256 * 2);
  f16* s3 = (f16*)alloc((size_t)25 * B * 512 * 2);
  f16* s4 = (f16*)alloc((size_t)25 * B * 1024 * 2);
  f16* Wc[5];
  for (int i = 1; i < 5; ++i)
    Wc[i] = (f16*)alloc((size_t)Ns[i] * Ks[i] * 2 * 2);

  float* outF = (float*)d_out;
  float* spk_rec = outF;
  float* mem_rec = outF + (size_t)25 * B * 784;

  // 2-split weights for layers 2..5
  for (int i = 1; i < 5; ++i) {
    const int total = Ns[i] * Ks[i];
    split2_kernel<<<(total + 255) / 256, 256, 0, stream>>>(W[i], Wc[i], total,
                                                           Ks[i]);
  }

  // layer-1 current: relu(x @ W1^T + b1), computed once (x is step-invariant)
  gemm_relu_f32_kernel<<<dim3(2, B / 64), 256, 0, stream>>>(x, W[0], bi[0],
                                                            cur1, 128, 100);

  // layer-1 LIF: full 25-step recurrence (cur1 fixed, mem in registers)
  lif1_kernel<<<(B * 128) / 1024, 256, 0, stream>>>(cur1, s1);

  // layers 2..5: one kernel each, 25 steps internal, mem in registers.
  // grid = NMT m-tiles x (N/(16*NF)) n-tiles; LDS = NK*NF*4096 bytes.
  layer_kernel<2, 2, 2><<<16 * 8, 256, 2 * 2 * 4096, stream>>>(
      s1, Wc[1], bi[1], s2, nullptr, nullptr, 256, 128, 0);
  layer_kernel<4, 2, 2><<<16 * 16, 256, 4 * 2 * 4096, stream>>>(
      s2, Wc[2], bi[2], s3, nullptr, nullptr, 512, 256, 0);
  layer_kernel<8, 2, 2><<<16 * 32, 256, 8 * 2 * 4096, stream>>>(
      s3, Wc[3], bi[3], s4, nullptr, nullptr, 1024, 512, 0);
  layer_kernel<16, 1, 4><<<8 * 49, 256, 16 * 1 * 4096, stream>>>(
      s4, Wc[4], bi[4], nullptr, spk_rec, mem_rec, 784, 1024, 1);
}